// Round 2
// baseline (561.860 us; speedup 1.0000x reference)
//
#include <hip/hip_runtime.h>
#include <cmath>

#define T_LEN 60000
#define BATCH 4
#define NBANDS 8
#define FB 32
#define EPS 1e-8f

__device__ __forceinline__ float logload(const float* row, int t, float gamma) {
    return (t >= 0 && t < T_LEN) ? __logf(fmaf(gamma, row[t], 1.0f)) : 0.f;
}

// ---------------- K1: x -> xp. grid (30, 8, 4), block 256; 8 outputs/thread.
// Barrier-free: float4 loads, log in regs, 5-tap halo via wave shuffles.
__global__ __launch_bounds__(256) void k1_xp(
        const float* __restrict__ x, const float* __restrict__ log_gamma,
        const float* __restrict__ diff_w, const float* __restrict__ diff_b,
        float* __restrict__ xp, int* __restrict__ mslots) {
    if (blockIdx.x == 0 && blockIdx.y == 0 && blockIdx.z == 0 && threadIdx.x < 8)
        mslots[threadIdx.x] = 0;  // zero m1[4], m2[4] (ws is poisoned 0xAA)
    const int tid = threadIdx.x, lane = tid & 63;
    const int band = blockIdx.y, b = blockIdx.z;
    const int t0 = blockIdx.x * 2048 + tid * 8;
    const float gamma = __expf(log_gamma[band]);
    float dw[5];
#pragma unroll
    for (int k = 0; k < 5; ++k) dw[k] = diff_w[band * 5 + k];
    const float db = diff_b[band];
    const float* base = x + ((size_t)(b * NBANDS + band) * FB) * T_LEN;
    float acc[8];
#pragma unroll
    for (int j = 0; j < 8; ++j) acc[j] = 0.f;
#pragma unroll 2
    for (int f = 0; f < FB; ++f) {
        const float* row = base + (size_t)f * T_LEN;
        float lv[8];
        if (t0 + 7 < T_LEN) {
            float4 v0 = *(const float4*)(row + t0);
            float4 v1 = *(const float4*)(row + t0 + 4);
            lv[0] = __logf(fmaf(gamma, v0.x, 1.f));
            lv[1] = __logf(fmaf(gamma, v0.y, 1.f));
            lv[2] = __logf(fmaf(gamma, v0.z, 1.f));
            lv[3] = __logf(fmaf(gamma, v0.w, 1.f));
            lv[4] = __logf(fmaf(gamma, v1.x, 1.f));
            lv[5] = __logf(fmaf(gamma, v1.y, 1.f));
            lv[6] = __logf(fmaf(gamma, v1.z, 1.f));
            lv[7] = __logf(fmaf(gamma, v1.w, 1.f));
        } else {
#pragma unroll
            for (int j = 0; j < 8; ++j) {
                int t = t0 + j;
                lv[j] = (t < T_LEN) ? __logf(fmaf(gamma, row[t], 1.f)) : 0.f;
            }
        }
        // halo: e[i] = value at t0 + i - 2
        float l2 = __shfl_up(lv[6], 1);
        float l1 = __shfl_up(lv[7], 1);
        float r0 = __shfl_down(lv[0], 1);
        float r1 = __shfl_down(lv[1], 1);
        if (lane == 0)       { l2 = logload(row, t0 - 2, gamma); l1 = logload(row, t0 - 1, gamma); }
        else if (lane == 63) { r0 = logload(row, t0 + 8, gamma); r1 = logload(row, t0 + 9, gamma); }
        float e[12] = {l2, l1, lv[0], lv[1], lv[2], lv[3], lv[4], lv[5], lv[6], lv[7], r0, r1};
#pragma unroll
        for (int j = 0; j < 8; ++j) {
            float xd = db;
#pragma unroll
            for (int k = 0; k < 5; ++k) xd = fmaf(dw[k], e[j + k], xd);
            acc[j] += fmaxf(xd, 0.f);
        }
    }
    if (t0 < T_LEN) {
        float* op = xp + ((size_t)(b * NBANDS + band)) * T_LEN + t0;
        if (t0 + 7 < T_LEN) {
            *(float4*)op       = make_float4(acc[0], acc[1], acc[2], acc[3]);
            *(float4*)(op + 4) = make_float4(acc[4], acc[5], acc[6], acc[7]);
        } else {
#pragma unroll
            for (int j = 0; j < 8; ++j)
                if (t0 + j < T_LEN) op[j] = acc[j];
        }
    }
}

// ---------------- K2: xp -> xg via composite 25-tap kernel (la+mix+gauss fused,
// all linear). grid (59, 4), block 256, tile 1024, 4 outputs/thread.
#define K2_TILE 1024
#define SW 1056  // stage [T0-16, T0+1040)
__global__ __launch_bounds__(256) void k2_xg(
        const float* __restrict__ xp,
        const float* __restrict__ la_w, const float* __restrict__ la_b,
        const float* __restrict__ mix_w, const float* __restrict__ g_w,
        const float* __restrict__ g_b,
        float* __restrict__ xg, int* __restrict__ m1_bits) {
    __shared__ float sh[NBANDS][SW];
    __shared__ float H[NBANDS][28];
    __shared__ float red[4];
    const int tid = threadIdx.x;
    const int T0 = blockIdx.x * K2_TILE;
    const int b = blockIdx.y;
    const float* xpb = xp + (size_t)b * NBANDS * T_LEN;
    // stage zero-padded xp tiles (float4)
    for (int idx = tid; idx < NBANDS * (SW / 4); idx += 256) {
        int c = idx / (SW / 4);
        int i4 = idx % (SW / 4);
        int g = T0 - 16 + 4 * i4;
        const float* rowp = xpb + (size_t)c * T_LEN;
        float4 v;
        if (g >= 0 && g + 3 < T_LEN) {
            v = *(const float4*)(rowp + g);
        } else {
            v.x = (g + 0 >= 0 && g + 0 < T_LEN) ? rowp[g + 0] : 0.f;
            v.y = (g + 1 >= 0 && g + 1 < T_LEN) ? rowp[g + 1] : 0.f;
            v.z = (g + 2 >= 0 && g + 2 < T_LEN) ? rowp[g + 2] : 0.f;
            v.w = (g + 3 >= 0 && g + 3 < T_LEN) ? rowp[g + 3] : 0.f;
        }
        *(float4*)&sh[c][4 * i4] = v;
    }
    // composite kernel H_c[m] = sum_{j+k=m} g_w[j] * mix_w[c]*(d[k==5]-la_w[c][k])
    if (tid < 200) {
        int c = tid / 25, m = tid % 25;
        int klo = m - 14 > 0 ? m - 14 : 0;
        int khi = m < 10 ? m : 10;
        float mw = mix_w[c], s = 0.f;
        for (int k = klo; k <= khi; ++k)
            s += g_w[m - k] * (mw * ((k == 5 ? 1.f : 0.f) - la_w[c * 11 + k]));
        H[c][m] = s;
    }
    float Sg = 0.f;
#pragma unroll
    for (int j = 0; j < 15; ++j) Sg += g_w[j];
    float C0 = 0.f;
#pragma unroll
    for (int c = 0; c < NBANDS; ++c) C0 -= mix_w[c] * la_b[c];
    const float cst = g_b[0] + Sg * C0;
    __syncthreads();
    const int basei = 4 * tid + 4;  // sh index of (t-12) for j=0
    float a0 = cst, a1 = cst, a2 = cst, a3 = cst;
#pragma unroll 1
    for (int c = 0; c < NBANDS; ++c) {
        float w[28];
#pragma unroll
        for (int q = 0; q < 7; ++q) {
            float4 v = *(const float4*)&sh[c][basei + 4 * q];
            w[4 * q] = v.x; w[4 * q + 1] = v.y; w[4 * q + 2] = v.z; w[4 * q + 3] = v.w;
        }
#pragma unroll
        for (int m = 0; m < 25; ++m) {
            float Hc = H[c][m];
            a0 = fmaf(Hc, w[m], a0);
            a1 = fmaf(Hc, w[m + 1], a1);
            a2 = fmaf(Hc, w[m + 2], a2);
            a3 = fmaf(Hc, w[m + 3], a3);
        }
    }
    float vout[4] = {a0, a1, a2, a3};
    float vmax = 0.f;
#pragma unroll
    for (int j = 0; j < 4; ++j) {
        int t = T0 + 4 * tid + j;
        float v = vout[j];
        if (t < 7 || (t >= T_LEN - 7 && t < T_LEN)) {
            // exact two-stage at the gaussian-conv padding boundary
            v = g_b[0];
            for (int jj = 0; jj < 15; ++jj) {
                int tp = t + jj - 7;
                if (tp < 0 || tp >= T_LEN) continue;
                float xm = C0;
                for (int c = 0; c < NBANDS; ++c) {
                    float mw = mix_w[c];
                    const float* rowp = xpb + (size_t)c * T_LEN;
                    for (int k = 0; k < 11; ++k) {
                        int ti = tp + k - 5;
                        float xv = (ti >= 0 && ti < T_LEN) ? rowp[ti] : 0.f;
                        xm = fmaf(mw * ((k == 5 ? 1.f : 0.f) - la_w[c * 11 + k]), xv, xm);
                    }
                }
                v = fmaf(g_w[jj], xm, v);
            }
        }
        if (t < T_LEN) {
            v = fmaxf(v, 0.f);
            xg[(size_t)b * T_LEN + t] = v;
            vmax = fmaxf(vmax, v);
        }
    }
#pragma unroll
    for (int off = 32; off > 0; off >>= 1) vmax = fmaxf(vmax, __shfl_down(vmax, off));
    if ((tid & 63) == 0) red[tid >> 6] = vmax;
    __syncthreads();
    if (tid == 0) {
        float m = fmaxf(fmaxf(red[0], red[1]), fmaxf(red[2], red[3]));
        atomicMax(&m1_bits[b], __float_as_int(m));
    }
}

// ---------------- K3a: xg -> spectral_flux out + fa (sigmoid) + max(fa)
__global__ __launch_bounds__(256) void k3a(
        const float* __restrict__ xg, const int* __restrict__ m1_bits,
        const float* __restrict__ fc_w, const float* __restrict__ fc_b,
        const float* __restrict__ fg_w, const float* __restrict__ fg_b,
        float* __restrict__ sf_out, float* __restrict__ fa_out,
        int* __restrict__ m2_bits) {
    __shared__ float shfm[272];
    __shared__ float red[4];
    const int tid = threadIdx.x;
    const int t0 = blockIdx.x * 256;
    const int b = blockIdx.y;
    const float inv = 1.f / (__int_as_float(m1_bits[b]) + EPS);
    const float sfc = fc_w[0] + fc_w[1] + fc_w[2] + fc_w[3];
    const float fcb = fc_b[0];
    for (int i = tid; i < 270; i += 256) {
        int tt = t0 + i - 7;
        float v = 0.f;  // fm zero-padded outside [0,T)
        if (tt >= 0 && tt < T_LEN)
            v = fmaf(sfc, xg[(size_t)b * T_LEN + tt] * inv, fcb);
        shfm[i] = v;
    }
    __syncthreads();
    const int t = t0 + tid;
    float fs = fg_b[0];
#pragma unroll
    for (int k = 0; k < 15; ++k) fs = fmaf(fg_w[k], shfm[tid + k], fs);
    float sig = 1.f / (1.f + __expf(-fs));
    float v;
    if (t < T_LEN) {
        sf_out[(size_t)b * T_LEN + t] = xg[(size_t)b * T_LEN + t] * inv;
        fa_out[(size_t)b * T_LEN + t] = sig;
        v = sig;
    } else {
        v = 0.f;
    }
#pragma unroll
    for (int off = 32; off > 0; off >>= 1) v = fmaxf(v, __shfl_down(v, off));
    if ((tid & 63) == 0) red[tid >> 6] = v;
    __syncthreads();
    if (tid == 0) {
        float m = fmaxf(fmaxf(red[0], red[1]), fmaxf(red[2], red[3]));
        atomicMax(&m2_bits[b], __float_as_int(m));
    }
}

// ---------------- K3b: fused_nov = fa / (m2 + eps), in-place
__global__ void k3b(float* __restrict__ fa, const int* __restrict__ m2_bits) {
    int idx = blockIdx.x * 256 + threadIdx.x;
    if (idx >= BATCH * T_LEN) return;
    int b = idx / T_LEN;
    float inv = 1.f / (__int_as_float(m2_bits[b]) + EPS);
    fa[idx] = fa[idx] * inv;
}

extern "C" void kernel_launch(void* const* d_in, const int* in_sizes, int n_in,
                              void* d_out, int out_size, void* d_ws, size_t ws_size,
                              hipStream_t stream) {
    const float* x    = (const float*)d_in[0];
    const float* lg   = (const float*)d_in[1];
    const float* dw   = (const float*)d_in[2];
    const float* db   = (const float*)d_in[3];
    const float* law  = (const float*)d_in[4];
    const float* lab  = (const float*)d_in[5];
    const float* mixw = (const float*)d_in[6];
    const float* gw   = (const float*)d_in[7];
    const float* gb   = (const float*)d_in[8];
    const float* fcw  = (const float*)d_in[9];
    const float* fcb  = (const float*)d_in[10];
    const float* fgw  = (const float*)d_in[11];
    const float* fgb  = (const float*)d_in[12];

    float* ws = (float*)d_ws;
    float* xp = ws;                                   // 4*8*60000 floats
    float* xg = ws + (size_t)BATCH * NBANDS * T_LEN;  // 240,000 floats
    int*   m1 = (int*)(xg + (size_t)BATCH * T_LEN);   // 4 ints
    // m2 = m1 + 4 (zeroed together with m1 in k1)

    float* sf_out = (float*)d_out;
    float* fn_out = sf_out + (size_t)BATCH * T_LEN;

    const int tb256 = (T_LEN + 255) / 256;

    k1_xp<<<dim3((T_LEN + 2047) / 2048, NBANDS, BATCH), dim3(256), 0, stream>>>(
        x, lg, dw, db, xp, m1);
    k2_xg<<<dim3((T_LEN + K2_TILE - 1) / K2_TILE, BATCH), dim3(256), 0, stream>>>(
        xp, law, lab, mixw, gw, gb, xg, m1);
    k3a<<<dim3(tb256, BATCH), dim3(256), 0, stream>>>(
        xg, m1, fcw, fcb, fgw, fgb, sf_out, fn_out, m1 + 4);
    k3b<<<dim3((BATCH * T_LEN + 255) / 256), dim3(256), 0, stream>>>(fn_out, m1 + 4);
}

// Round 3
// 436.594 us; speedup vs baseline: 1.2869x; 1.2869x over previous
//
#include <hip/hip_runtime.h>
#include <cmath>

#define T_LEN 60000
#define BATCH 4
#define NBANDS 8
#define FB 32
#define EPS 1e-8f

typedef float f4u __attribute__((ext_vector_type(4), aligned(4)));

__device__ __forceinline__ float logload(const float* row, int t, float gamma) {
    return (t >= 0 && t < T_LEN) ? __logf(fmaf(gamma, row[t], 1.0f)) : 0.f;
}

// ---------------- K1: x -> xp. grid (59, 8, 4), block 256; 4 outputs/thread.
// No barriers, no shuffles: each thread loads its 8 needed floats [t0-2, t0+5]
// as two adjacent (4B-aligned) dwordx4 loads, logs in regs, 5-tap diff, relu, acc.
__global__ __launch_bounds__(256) void k1_xp(
        const float* __restrict__ x, const float* __restrict__ log_gamma,
        const float* __restrict__ diff_w, const float* __restrict__ diff_b,
        float* __restrict__ xp, int* __restrict__ mslots) {
    if (blockIdx.x == 0 && blockIdx.y == 0 && blockIdx.z == 0 && threadIdx.x < 8)
        mslots[threadIdx.x] = 0;  // zero m1[4], m2[4] (ws poisoned 0xAA)
    const int tid = threadIdx.x;
    const int band = blockIdx.y, b = blockIdx.z;
    const int t0 = blockIdx.x * 1024 + tid * 4;
    const float gamma = __expf(log_gamma[band]);
    float dw[5];
#pragma unroll
    for (int k = 0; k < 5; ++k) dw[k] = diff_w[band * 5 + k];
    const float db = diff_b[band];
    const float* base = x + ((size_t)(b * NBANDS + band) * FB) * T_LEN;
    float acc[4] = {0.f, 0.f, 0.f, 0.f};
    const bool fast = (t0 >= 2) && (t0 + 5 < T_LEN);
    if (fast) {
#pragma unroll 4
        for (int f = 0; f < FB; ++f) {
            const float* row = base + (size_t)f * T_LEN;
            f4u va = *(const f4u*)(row + t0 - 2);
            f4u vb = *(const f4u*)(row + t0 + 2);
            float e[8];
            e[0] = __logf(fmaf(gamma, va.x, 1.f));
            e[1] = __logf(fmaf(gamma, va.y, 1.f));
            e[2] = __logf(fmaf(gamma, va.z, 1.f));
            e[3] = __logf(fmaf(gamma, va.w, 1.f));
            e[4] = __logf(fmaf(gamma, vb.x, 1.f));
            e[5] = __logf(fmaf(gamma, vb.y, 1.f));
            e[6] = __logf(fmaf(gamma, vb.z, 1.f));
            e[7] = __logf(fmaf(gamma, vb.w, 1.f));
#pragma unroll
            for (int j = 0; j < 4; ++j) {
                float xd = db;
#pragma unroll
                for (int k = 0; k < 5; ++k) xd = fmaf(dw[k], e[j + k], xd);
                acc[j] += fmaxf(xd, 0.f);
            }
        }
    } else if (t0 < T_LEN) {
        for (int f = 0; f < FB; ++f) {
            const float* row = base + (size_t)f * T_LEN;
            float e[8];
#pragma unroll
            for (int i = 0; i < 8; ++i) e[i] = logload(row, t0 - 2 + i, gamma);
#pragma unroll
            for (int j = 0; j < 4; ++j) {
                float xd = db;
#pragma unroll
                for (int k = 0; k < 5; ++k) xd = fmaf(dw[k], e[j + k], xd);
                acc[j] += fmaxf(xd, 0.f);
            }
        }
    }
    if (t0 < T_LEN) {
        float* op = xp + ((size_t)(b * NBANDS + band)) * T_LEN + t0;
        if (t0 + 3 < T_LEN) {
            *(float4*)op = make_float4(acc[0], acc[1], acc[2], acc[3]);
        } else {
#pragma unroll
            for (int j = 0; j < 4; ++j)
                if (t0 + j < T_LEN) op[j] = acc[j];
        }
    }
}

// ---------------- K2: xp -> xg via composite 25-tap kernel (la-subtract + band
// mix + gaussian fused; all linear). Tile 256, 1 output/thread, stride-1 LDS.
// Boundary t (<7 or >=T-7) recomputed two-stage FROM LDS (no global loads).
#define K2_STAGE 288  // [T0-16, T0+272)
__global__ __launch_bounds__(256) void k2_xg(
        const float* __restrict__ xp,
        const float* __restrict__ la_w, const float* __restrict__ la_b,
        const float* __restrict__ mix_w, const float* __restrict__ g_w,
        const float* __restrict__ g_b,
        float* __restrict__ xg, int* __restrict__ m1_bits) {
    __shared__ float sh[NBANDS][K2_STAGE];
    __shared__ float H[NBANDS][25];
    __shared__ float red[4];
    const int tid = threadIdx.x;
    const int T0 = blockIdx.x * 256;
    const int b = blockIdx.y;
    const float* xpb = xp + (size_t)b * NBANDS * T_LEN;
    // stage zero-padded xp tiles (float4), 288 floats per band
    for (int idx = tid; idx < NBANDS * (K2_STAGE / 4); idx += 256) {
        int c = idx / (K2_STAGE / 4);
        int i4 = idx % (K2_STAGE / 4);
        int g = T0 - 16 + 4 * i4;
        const float* rowp = xpb + (size_t)c * T_LEN;
        float4 v;
        if (g >= 0 && g + 3 < T_LEN) {
            v = *(const float4*)(rowp + g);
        } else {
            v.x = (g + 0 >= 0 && g + 0 < T_LEN) ? rowp[g + 0] : 0.f;
            v.y = (g + 1 >= 0 && g + 1 < T_LEN) ? rowp[g + 1] : 0.f;
            v.z = (g + 2 >= 0 && g + 2 < T_LEN) ? rowp[g + 2] : 0.f;
            v.w = (g + 3 >= 0 && g + 3 < T_LEN) ? rowp[g + 3] : 0.f;
        }
        *(float4*)&sh[c][4 * i4] = v;
    }
    // composite kernel H_c[m] = sum_{j+k=m} g_w[j] * mix_w[c]*((k==5)-la_w[c][k])
    if (tid < 200) {
        int c = tid / 25, m = tid % 25;
        int klo = m - 14 > 0 ? m - 14 : 0;
        int khi = m < 10 ? m : 10;
        float mw = mix_w[c], s = 0.f;
        for (int k = klo; k <= khi; ++k)
            s += g_w[m - k] * (mw * ((k == 5 ? 1.f : 0.f) - la_w[c * 11 + k]));
        H[c][m] = s;
    }
    float Sg = 0.f;
#pragma unroll
    for (int j = 0; j < 15; ++j) Sg += g_w[j];
    float C0 = 0.f;
#pragma unroll
    for (int c = 0; c < NBANDS; ++c) C0 -= mix_w[c] * la_b[c];
    const float cst = g_b[0] + Sg * C0;
    __syncthreads();
    const int t = T0 + tid;
    float v = cst;
#pragma unroll 1
    for (int c = 0; c < NBANDS; ++c) {
        float a = 0.f;
#pragma unroll
        for (int m = 0; m < 25; ++m) a = fmaf(H[c][m], sh[c][tid + 4 + m], a);
        v += a;
    }
    if (t < 7 || (t >= T_LEN - 7 && t < T_LEN)) {
        // exact two-stage at the gaussian padding boundary — reads LDS only
        v = g_b[0];
        for (int jj = 0; jj < 15; ++jj) {
            int tp = t + jj - 7;
            if (tp < 0 || tp >= T_LEN) continue;
            float xm = C0;
            for (int c = 0; c < NBANDS; ++c) {
                float mw = mix_w[c];
                for (int k = 0; k < 11; ++k) {
                    int i = tp + k + 11 - T0;  // sh idx of xp[tp+k-5], zero-padded
                    xm = fmaf(mw * ((k == 5 ? 1.f : 0.f) - la_w[c * 11 + k]),
                              sh[c][i], xm);
                }
            }
            v = fmaf(g_w[jj], xm, v);
        }
    }
    float vmax = 0.f;
    if (t < T_LEN) {
        v = fmaxf(v, 0.f);
        xg[(size_t)b * T_LEN + t] = v;
        vmax = v;
    }
#pragma unroll
    for (int off = 32; off > 0; off >>= 1) vmax = fmaxf(vmax, __shfl_down(vmax, off));
    if ((tid & 63) == 0) red[tid >> 6] = vmax;
    __syncthreads();
    if (tid == 0) {
        float m = fmaxf(fmaxf(red[0], red[1]), fmaxf(red[2], red[3]));
        atomicMax(&m1_bits[b], __float_as_int(m));
    }
}

// ---------------- K3a: xg -> spectral_flux out + fa (sigmoid) + max(fa)
__global__ __launch_bounds__(256) void k3a(
        const float* __restrict__ xg, const int* __restrict__ m1_bits,
        const float* __restrict__ fc_w, const float* __restrict__ fc_b,
        const float* __restrict__ fg_w, const float* __restrict__ fg_b,
        float* __restrict__ sf_out, float* __restrict__ fa_out,
        int* __restrict__ m2_bits) {
    __shared__ float shfm[272];
    __shared__ float red[4];
    const int tid = threadIdx.x;
    const int t0 = blockIdx.x * 256;
    const int b = blockIdx.y;
    const float inv = 1.f / (__int_as_float(m1_bits[b]) + EPS);
    const float sfc = fc_w[0] + fc_w[1] + fc_w[2] + fc_w[3];
    const float fcb = fc_b[0];
    for (int i = tid; i < 270; i += 256) {
        int tt = t0 + i - 7;
        float v = 0.f;  // fm zero-padded outside [0,T)
        if (tt >= 0 && tt < T_LEN)
            v = fmaf(sfc, xg[(size_t)b * T_LEN + tt] * inv, fcb);
        shfm[i] = v;
    }
    __syncthreads();
    const int t = t0 + tid;
    float fs = fg_b[0];
#pragma unroll
    for (int k = 0; k < 15; ++k) fs = fmaf(fg_w[k], shfm[tid + k], fs);
    float sig = 1.f / (1.f + __expf(-fs));
    float v;
    if (t < T_LEN) {
        sf_out[(size_t)b * T_LEN + t] = xg[(size_t)b * T_LEN + t] * inv;
        fa_out[(size_t)b * T_LEN + t] = sig;
        v = sig;
    } else {
        v = 0.f;
    }
#pragma unroll
    for (int off = 32; off > 0; off >>= 1) v = fmaxf(v, __shfl_down(v, off));
    if ((tid & 63) == 0) red[tid >> 6] = v;
    __syncthreads();
    if (tid == 0) {
        float m = fmaxf(fmaxf(red[0], red[1]), fmaxf(red[2], red[3]));
        atomicMax(&m2_bits[b], __float_as_int(m));
    }
}

// ---------------- K3b: fused_nov = fa / (m2 + eps), in-place
__global__ void k3b(float* __restrict__ fa, const int* __restrict__ m2_bits) {
    int idx = blockIdx.x * 256 + threadIdx.x;
    if (idx >= BATCH * T_LEN) return;
    int b = idx / T_LEN;
    float inv = 1.f / (__int_as_float(m2_bits[b]) + EPS);
    fa[idx] = fa[idx] * inv;
}

extern "C" void kernel_launch(void* const* d_in, const int* in_sizes, int n_in,
                              void* d_out, int out_size, void* d_ws, size_t ws_size,
                              hipStream_t stream) {
    const float* x    = (const float*)d_in[0];
    const float* lg   = (const float*)d_in[1];
    const float* dw   = (const float*)d_in[2];
    const float* db   = (const float*)d_in[3];
    const float* law  = (const float*)d_in[4];
    const float* lab  = (const float*)d_in[5];
    const float* mixw = (const float*)d_in[6];
    const float* gw   = (const float*)d_in[7];
    const float* gb   = (const float*)d_in[8];
    const float* fcw  = (const float*)d_in[9];
    const float* fcb  = (const float*)d_in[10];
    const float* fgw  = (const float*)d_in[11];
    const float* fgb  = (const float*)d_in[12];

    float* ws = (float*)d_ws;
    float* xp = ws;                                   // 4*8*60000 floats
    float* xg = ws + (size_t)BATCH * NBANDS * T_LEN;  // 240,000 floats
    int*   m1 = (int*)(xg + (size_t)BATCH * T_LEN);   // m1[4] then m2[4]

    float* sf_out = (float*)d_out;
    float* fn_out = sf_out + (size_t)BATCH * T_LEN;

    const int tb256 = (T_LEN + 255) / 256;

    k1_xp<<<dim3((T_LEN + 1023) / 1024, NBANDS, BATCH), dim3(256), 0, stream>>>(
        x, lg, dw, db, xp, m1);
    k2_xg<<<dim3(tb256, BATCH), dim3(256), 0, stream>>>(
        xp, law, lab, mixw, gw, gb, xg, m1);
    k3a<<<dim3(tb256, BATCH), dim3(256), 0, stream>>>(
        xg, m1, fcw, fcb, fgw, fgb, sf_out, fn_out, m1 + 4);
    k3b<<<dim3((BATCH * T_LEN + 255) / 256), dim3(256), 0, stream>>>(fn_out, m1 + 4);
}

// Round 4
// 429.055 us; speedup vs baseline: 1.3095x; 1.0176x over previous
//
#include <hip/hip_runtime.h>
#include <cmath>

#define T_LEN 60000
#define BATCH 4
#define NBANDS 8
#define FB 32
#define EPS 1e-8f

__device__ __forceinline__ float logload(const float* row, int t, float gamma) {
    return (t >= 0 && t < T_LEN) ? __logf(fmaf(gamma, row[t], 1.0f)) : 0.f;
}

// ---------------- K1: x -> xp. grid (118, 8, 4), block 256 = 4 waves.
// Each wave reduces 8 of the 32 f-rows over a 512-t tile (8 t/lane, aligned
// 2x float4, halo via shuffles); partials summed via one LDS pass.
__global__ __launch_bounds__(256) void k1_xp(
        const float* __restrict__ x, const float* __restrict__ log_gamma,
        const float* __restrict__ diff_w, const float* __restrict__ diff_b,
        float* __restrict__ xp, int* __restrict__ mslots) {
    if (blockIdx.x == 0 && blockIdx.y == 0 && blockIdx.z == 0 && threadIdx.x < 8)
        mslots[threadIdx.x] = 0;  // zero m1[4], m2[4] (ws poisoned 0xAA)
    __shared__ float sh[4][512];
    const int tid = threadIdx.x, lane = tid & 63, w = tid >> 6;
    const int band = blockIdx.y, b = blockIdx.z;
    const int tile0 = blockIdx.x * 512;
    const int t0 = tile0 + lane * 8;
    const float gamma = __expf(log_gamma[band]);
    float dw[5];
#pragma unroll
    for (int k = 0; k < 5; ++k) dw[k] = diff_w[band * 5 + k];
    const float db = diff_b[band];
    const float* row = x + ((size_t)((b * NBANDS + band) * FB + w * 8)) * T_LEN;
    float acc[8] = {0.f, 0.f, 0.f, 0.f, 0.f, 0.f, 0.f, 0.f};

    if (tile0 + 512 <= T_LEN) {  // wave-uniform fast path: vector loads in-bounds
        float4 c0 = *(const float4*)(row + t0);
        float4 c1 = *(const float4*)(row + t0 + 4);
#pragma unroll
        for (int ff = 0; ff < 8; ++ff) {
            const float* nrow = row + T_LEN;
            float4 n0 = c0, n1 = c1;
            if (ff < 7) {  // prefetch next row before using current
                n0 = *(const float4*)(nrow + t0);
                n1 = *(const float4*)(nrow + t0 + 4);
            }
            float lv[8];
            lv[0] = __logf(fmaf(gamma, c0.x, 1.f));
            lv[1] = __logf(fmaf(gamma, c0.y, 1.f));
            lv[2] = __logf(fmaf(gamma, c0.z, 1.f));
            lv[3] = __logf(fmaf(gamma, c0.w, 1.f));
            lv[4] = __logf(fmaf(gamma, c1.x, 1.f));
            lv[5] = __logf(fmaf(gamma, c1.y, 1.f));
            lv[6] = __logf(fmaf(gamma, c1.z, 1.f));
            lv[7] = __logf(fmaf(gamma, c1.w, 1.f));
            float l2 = __shfl_up(lv[6], 1);
            float l1 = __shfl_up(lv[7], 1);
            float r0 = __shfl_down(lv[0], 1);
            float r1 = __shfl_down(lv[1], 1);
            if (lane == 0)       { l2 = logload(row, t0 - 2, gamma); l1 = logload(row, t0 - 1, gamma); }
            else if (lane == 63) { r0 = logload(row, t0 + 8, gamma); r1 = logload(row, t0 + 9, gamma); }
            float e[12] = {l2, l1, lv[0], lv[1], lv[2], lv[3], lv[4], lv[5], lv[6], lv[7], r0, r1};
#pragma unroll
            for (int j = 0; j < 8; ++j) {
                float xd = db;
#pragma unroll
                for (int k = 0; k < 5; ++k) xd = fmaf(dw[k], e[j + k], xd);
                acc[j] += fmaxf(xd, 0.f);
            }
            row = nrow; c0 = n0; c1 = n1;
        }
    } else {  // tail tile: predicated scalar path
        for (int ff = 0; ff < 8; ++ff) {
            float e[12];
#pragma unroll
            for (int i = 0; i < 12; ++i) e[i] = logload(row, t0 - 2 + i, gamma);
#pragma unroll
            for (int j = 0; j < 8; ++j) {
                float xd = db;
#pragma unroll
                for (int k = 0; k < 5; ++k) xd = fmaf(dw[k], e[j + k], xd);
                acc[j] += fmaxf(xd, 0.f);
            }
            row += T_LEN;
        }
    }
    *(float4*)&sh[w][lane * 8]     = make_float4(acc[0], acc[1], acc[2], acc[3]);
    *(float4*)&sh[w][lane * 8 + 4] = make_float4(acc[4], acc[5], acc[6], acc[7]);
    __syncthreads();
    if (tid < 128) {
        const int i = tid * 4;
        const int t = tile0 + i;
        float4 s0 = *(const float4*)&sh[0][i];
        float4 s1 = *(const float4*)&sh[1][i];
        float4 s2 = *(const float4*)&sh[2][i];
        float4 s3 = *(const float4*)&sh[3][i];
        float4 o = make_float4(s0.x + s1.x + s2.x + s3.x,
                               s0.y + s1.y + s2.y + s3.y,
                               s0.z + s1.z + s2.z + s3.z,
                               s0.w + s1.w + s2.w + s3.w);
        float* op = xp + ((size_t)(b * NBANDS + band)) * T_LEN + t;
        if (t + 4 <= T_LEN) {
            *(float4*)op = o;
        } else if (t < T_LEN) {
            const float* of = (const float*)&o;
            for (int j = 0; j < 4 && t + j < T_LEN; ++j) op[j] = of[j];
        }
    }
}

// ---------------- K2: xp -> xg via composite 25-tap kernel (la-subtract + band
// mix + gaussian fused; all linear). Tile 256, 1 output/thread, stride-1 LDS.
// Boundary t (<7 or >=T-7) recomputed two-stage FROM LDS (no global loads).
#define K2_STAGE 288  // [T0-16, T0+272)
__global__ __launch_bounds__(256) void k2_xg(
        const float* __restrict__ xp,
        const float* __restrict__ la_w, const float* __restrict__ la_b,
        const float* __restrict__ mix_w, const float* __restrict__ g_w,
        const float* __restrict__ g_b,
        float* __restrict__ xg, int* __restrict__ m1_bits) {
    __shared__ float sh[NBANDS][K2_STAGE];
    __shared__ float H[NBANDS][25];
    __shared__ float red[4];
    const int tid = threadIdx.x;
    const int T0 = blockIdx.x * 256;
    const int b = blockIdx.y;
    const float* xpb = xp + (size_t)b * NBANDS * T_LEN;
    for (int idx = tid; idx < NBANDS * (K2_STAGE / 4); idx += 256) {
        int c = idx / (K2_STAGE / 4);
        int i4 = idx % (K2_STAGE / 4);
        int g = T0 - 16 + 4 * i4;
        const float* rowp = xpb + (size_t)c * T_LEN;
        float4 v;
        if (g >= 0 && g + 3 < T_LEN) {
            v = *(const float4*)(rowp + g);
        } else {
            v.x = (g + 0 >= 0 && g + 0 < T_LEN) ? rowp[g + 0] : 0.f;
            v.y = (g + 1 >= 0 && g + 1 < T_LEN) ? rowp[g + 1] : 0.f;
            v.z = (g + 2 >= 0 && g + 2 < T_LEN) ? rowp[g + 2] : 0.f;
            v.w = (g + 3 >= 0 && g + 3 < T_LEN) ? rowp[g + 3] : 0.f;
        }
        *(float4*)&sh[c][4 * i4] = v;
    }
    if (tid < 200) {
        int c = tid / 25, m = tid % 25;
        int klo = m - 14 > 0 ? m - 14 : 0;
        int khi = m < 10 ? m : 10;
        float mw = mix_w[c], s = 0.f;
        for (int k = klo; k <= khi; ++k)
            s += g_w[m - k] * (mw * ((k == 5 ? 1.f : 0.f) - la_w[c * 11 + k]));
        H[c][m] = s;
    }
    float Sg = 0.f;
#pragma unroll
    for (int j = 0; j < 15; ++j) Sg += g_w[j];
    float C0 = 0.f;
#pragma unroll
    for (int c = 0; c < NBANDS; ++c) C0 -= mix_w[c] * la_b[c];
    const float cst = g_b[0] + Sg * C0;
    __syncthreads();
    const int t = T0 + tid;
    float v = cst;
#pragma unroll 1
    for (int c = 0; c < NBANDS; ++c) {
        float a = 0.f;
#pragma unroll
        for (int m = 0; m < 25; ++m) a = fmaf(H[c][m], sh[c][tid + 4 + m], a);
        v += a;
    }
    if (t < 7 || (t >= T_LEN - 7 && t < T_LEN)) {
        v = g_b[0];
        for (int jj = 0; jj < 15; ++jj) {
            int tp = t + jj - 7;
            if (tp < 0 || tp >= T_LEN) continue;
            float xm = C0;
            for (int c = 0; c < NBANDS; ++c) {
                float mw = mix_w[c];
                for (int k = 0; k < 11; ++k) {
                    int i = tp + k + 11 - T0;
                    xm = fmaf(mw * ((k == 5 ? 1.f : 0.f) - la_w[c * 11 + k]),
                              sh[c][i], xm);
                }
            }
            v = fmaf(g_w[jj], xm, v);
        }
    }
    float vmax = 0.f;
    if (t < T_LEN) {
        v = fmaxf(v, 0.f);
        xg[(size_t)b * T_LEN + t] = v;
        vmax = v;
    }
#pragma unroll
    for (int off = 32; off > 0; off >>= 1) vmax = fmaxf(vmax, __shfl_down(vmax, off));
    if ((tid & 63) == 0) red[tid >> 6] = vmax;
    __syncthreads();
    if (tid == 0) {
        float m = fmaxf(fmaxf(red[0], red[1]), fmaxf(red[2], red[3]));
        atomicMax(&m1_bits[b], __float_as_int(m));
    }
}

// ---------------- K3a: xg -> spectral_flux out + fa (sigmoid) + max(fa)
__global__ __launch_bounds__(256) void k3a(
        const float* __restrict__ xg, const int* __restrict__ m1_bits,
        const float* __restrict__ fc_w, const float* __restrict__ fc_b,
        const float* __restrict__ fg_w, const float* __restrict__ fg_b,
        float* __restrict__ sf_out, float* __restrict__ fa_out,
        int* __restrict__ m2_bits) {
    __shared__ float shfm[272];
    __shared__ float red[4];
    const int tid = threadIdx.x;
    const int t0 = blockIdx.x * 256;
    const int b = blockIdx.y;
    const float inv = 1.f / (__int_as_float(m1_bits[b]) + EPS);
    const float sfc = fc_w[0] + fc_w[1] + fc_w[2] + fc_w[3];
    const float fcb = fc_b[0];
    for (int i = tid; i < 270; i += 256) {
        int tt = t0 + i - 7;
        float v = 0.f;
        if (tt >= 0 && tt < T_LEN)
            v = fmaf(sfc, xg[(size_t)b * T_LEN + tt] * inv, fcb);
        shfm[i] = v;
    }
    __syncthreads();
    const int t = t0 + tid;
    float fs = fg_b[0];
#pragma unroll
    for (int k = 0; k < 15; ++k) fs = fmaf(fg_w[k], shfm[tid + k], fs);
    float sig = 1.f / (1.f + __expf(-fs));
    float v;
    if (t < T_LEN) {
        sf_out[(size_t)b * T_LEN + t] = xg[(size_t)b * T_LEN + t] * inv;
        fa_out[(size_t)b * T_LEN + t] = sig;
        v = sig;
    } else {
        v = 0.f;
    }
#pragma unroll
    for (int off = 32; off > 0; off >>= 1) v = fmaxf(v, __shfl_down(v, off));
    if ((tid & 63) == 0) red[tid >> 6] = v;
    __syncthreads();
    if (tid == 0) {
        float m = fmaxf(fmaxf(red[0], red[1]), fmaxf(red[2], red[3]));
        atomicMax(&m2_bits[b], __float_as_int(m));
    }
}

// ---------------- K3b: fused_nov = fa / (m2 + eps), in-place
__global__ void k3b(float* __restrict__ fa, const int* __restrict__ m2_bits) {
    int idx = blockIdx.x * 256 + threadIdx.x;
    if (idx >= BATCH * T_LEN) return;
    int b = idx / T_LEN;
    float inv = 1.f / (__int_as_float(m2_bits[b]) + EPS);
    fa[idx] = fa[idx] * inv;
}

extern "C" void kernel_launch(void* const* d_in, const int* in_sizes, int n_in,
                              void* d_out, int out_size, void* d_ws, size_t ws_size,
                              hipStream_t stream) {
    const float* x    = (const float*)d_in[0];
    const float* lg   = (const float*)d_in[1];
    const float* dw   = (const float*)d_in[2];
    const float* db   = (const float*)d_in[3];
    const float* law  = (const float*)d_in[4];
    const float* lab  = (const float*)d_in[5];
    const float* mixw = (const float*)d_in[6];
    const float* gw   = (const float*)d_in[7];
    const float* gb   = (const float*)d_in[8];
    const float* fcw  = (const float*)d_in[9];
    const float* fcb  = (const float*)d_in[10];
    const float* fgw  = (const float*)d_in[11];
    const float* fgb  = (const float*)d_in[12];

    float* ws = (float*)d_ws;
    float* xp = ws;                                   // 4*8*60000 floats
    float* xg = ws + (size_t)BATCH * NBANDS * T_LEN;  // 240,000 floats
    int*   m1 = (int*)(xg + (size_t)BATCH * T_LEN);   // m1[4] then m2[4]

    float* sf_out = (float*)d_out;
    float* fn_out = sf_out + (size_t)BATCH * T_LEN;

    const int tb256 = (T_LEN + 255) / 256;

    k1_xp<<<dim3((T_LEN + 511) / 512, NBANDS, BATCH), dim3(256), 0, stream>>>(
        x, lg, dw, db, xp, m1);
    k2_xg<<<dim3(tb256, BATCH), dim3(256), 0, stream>>>(
        xp, law, lab, mixw, gw, gb, xg, m1);
    k3a<<<dim3(tb256, BATCH), dim3(256), 0, stream>>>(
        xg, m1, fcw, fcb, fgw, fgb, sf_out, fn_out, m1 + 4);
    k3b<<<dim3((BATCH * T_LEN + 255) / 256), dim3(256), 0, stream>>>(fn_out, m1 + 4);
}

// Round 6
// 412.769 us; speedup vs baseline: 1.3612x; 1.0395x over previous
//
#include <hip/hip_runtime.h>
#include <cmath>

#define T_LEN 60000
#define BATCH 4
#define NBANDS 8
#define FB 32
#define EPS 1e-8f

#define K1_TILE 496
#define K1_ROWLEN 512   // staged floats per row: window [tile0-8, tile0+504)
#define K1_NBX ((T_LEN + K1_TILE - 1) / K1_TILE)   // 121

// ---------------- K1: x -> xp. grid (121, 8, 4), block 256.
// m97 pattern: bulk-stage 32 rows x 512 floats of RAW x into LDS (16
// independent float4 loads/thread in flight), ONE barrier, then compute
// log -> 5-tap diff -> relu -> f-sum entirely from LDS. Zero-padding is
// staged as raw 0 (log(g*0+1)=0 reproduces the conv's zero-padded xl).
__global__ __launch_bounds__(256) void k1_xp(
        const float* __restrict__ x, const float* __restrict__ log_gamma,
        const float* __restrict__ diff_w, const float* __restrict__ diff_b,
        float* __restrict__ xp, int* __restrict__ mslots) {
    extern __shared__ float sh[];   // 32 * 512 floats = 64 KB
    const int tid = threadIdx.x;
    const int bx = blockIdx.x, band = blockIdx.y, b = blockIdx.z;
    if (bx == 0 && band == 0 && b == 0 && tid < 8)
        mslots[tid] = 0;  // zero m1[4], m2[4] (ws poisoned 0xAA)
    const int tile0 = bx * K1_TILE;
    const int w0 = tile0 - 8;  // global t of sh[r][0]
    const float* base = x + ((size_t)((b * NBANDS + band) * FB)) * T_LEN;
    const bool interior = (w0 >= 0) && (w0 + K1_ROWLEN <= T_LEN);
    if (interior) {
        // 16 chunks of 1024 floats: 256 threads x float4 covers all 16384
#pragma unroll
        for (int c = 0; c < 16; ++c) {
            const int idx = c * 1024 + tid * 4;   // float index into sh
            const int r = idx >> 9;               // row 0..31
            const int i = idx & 511;              // 16B-aligned (w0%4==0, i%4==0)
            float4 v = *(const float4*)(base + (size_t)r * T_LEN + w0 + i);
            *(float4*)&sh[idx] = v;
        }
    } else {  // bx==0 or last: predicated scalar staging (wave-uniform branch)
        for (int c = 0; c < 16; ++c) {
            const int idx = c * 1024 + tid * 4;
            const int r = idx >> 9;
            const int i = idx & 511;
            const float* rowp = base + (size_t)r * T_LEN;
#pragma unroll
            for (int j = 0; j < 4; ++j) {
                const int t = w0 + i + j;
                sh[idx + j] = (t >= 0 && t < T_LEN) ? rowp[t] : 0.f;
            }
        }
    }
    __syncthreads();
    const float gamma = __expf(log_gamma[band]);
    float dw[5];
#pragma unroll
    for (int k = 0; k < 5; ++k) dw[k] = diff_w[band * 5 + k];
    const float db = diff_b[band];
    const int t0 = tile0 + 2 * tid;
    if (tid < 248 && t0 < T_LEN) {
        float acc0 = 0.f, acc1 = 0.f;
        const int i0 = 2 * tid + 6;  // sh row-index of t0-2 (8B-aligned)
#pragma unroll 4
        for (int r = 0; r < FB; ++r) {
            const float* rp = &sh[r * K1_ROWLEN];
            float2 pa = *(const float2*)(rp + i0);
            float2 pb = *(const float2*)(rp + i0 + 2);
            float2 pc = *(const float2*)(rp + i0 + 4);
            float e0 = __logf(fmaf(gamma, pa.x, 1.f));
            float e1 = __logf(fmaf(gamma, pa.y, 1.f));
            float e2 = __logf(fmaf(gamma, pb.x, 1.f));
            float e3 = __logf(fmaf(gamma, pb.y, 1.f));
            float e4 = __logf(fmaf(gamma, pc.x, 1.f));
            float e5 = __logf(fmaf(gamma, pc.y, 1.f));
            float xd0 = db, xd1 = db;
            xd0 = fmaf(dw[0], e0, xd0); xd1 = fmaf(dw[0], e1, xd1);
            xd0 = fmaf(dw[1], e1, xd0); xd1 = fmaf(dw[1], e2, xd1);
            xd0 = fmaf(dw[2], e2, xd0); xd1 = fmaf(dw[2], e3, xd1);
            xd0 = fmaf(dw[3], e3, xd0); xd1 = fmaf(dw[3], e4, xd1);
            xd0 = fmaf(dw[4], e4, xd0); xd1 = fmaf(dw[4], e5, xd1);
            acc0 += fmaxf(xd0, 0.f);
            acc1 += fmaxf(xd1, 0.f);
        }
        float* op = xp + ((size_t)(b * NBANDS + band)) * T_LEN + t0;
        op[0] = acc0;
        if (t0 + 1 < T_LEN) op[1] = acc1;
    }
}

// ---------------- K2: xp -> xg via composite 25-tap kernel (la-subtract + band
// mix + gaussian fused; all linear). Tile 256, 1 output/thread, stride-1 LDS.
// Boundary t (<7 or >=T-7) recomputed two-stage FROM LDS (no global loads).
#define K2_STAGE 288  // [T0-16, T0+272)
__global__ __launch_bounds__(256) void k2_xg(
        const float* __restrict__ xp,
        const float* __restrict__ la_w, const float* __restrict__ la_b,
        const float* __restrict__ mix_w, const float* __restrict__ g_w,
        const float* __restrict__ g_b,
        float* __restrict__ xg, int* __restrict__ m1_bits) {
    __shared__ float sh[NBANDS][K2_STAGE];
    __shared__ float H[NBANDS][25];
    __shared__ float red[4];
    const int tid = threadIdx.x;
    const int T0 = blockIdx.x * 256;
    const int b = blockIdx.y;
    const float* xpb = xp + (size_t)b * NBANDS * T_LEN;
    for (int idx = tid; idx < NBANDS * (K2_STAGE / 4); idx += 256) {
        int c = idx / (K2_STAGE / 4);
        int i4 = idx % (K2_STAGE / 4);
        int g = T0 - 16 + 4 * i4;
        const float* rowp = xpb + (size_t)c * T_LEN;
        float4 v;
        if (g >= 0 && g + 3 < T_LEN) {
            v = *(const float4*)(rowp + g);
        } else {
            v.x = (g + 0 >= 0 && g + 0 < T_LEN) ? rowp[g + 0] : 0.f;
            v.y = (g + 1 >= 0 && g + 1 < T_LEN) ? rowp[g + 1] : 0.f;
            v.z = (g + 2 >= 0 && g + 2 < T_LEN) ? rowp[g + 2] : 0.f;
            v.w = (g + 3 >= 0 && g + 3 < T_LEN) ? rowp[g + 3] : 0.f;
        }
        *(float4*)&sh[c][4 * i4] = v;
    }
    if (tid < 200) {
        int c = tid / 25, m = tid % 25;
        int klo = m - 14 > 0 ? m - 14 : 0;
        int khi = m < 10 ? m : 10;
        float mw = mix_w[c], s = 0.f;
        for (int k = klo; k <= khi; ++k)
            s += g_w[m - k] * (mw * ((k == 5 ? 1.f : 0.f) - la_w[c * 11 + k]));
        H[c][m] = s;
    }
    float Sg = 0.f;
#pragma unroll
    for (int j = 0; j < 15; ++j) Sg += g_w[j];
    float C0 = 0.f;
#pragma unroll
    for (int c = 0; c < NBANDS; ++c) C0 -= mix_w[c] * la_b[c];
    const float cst = g_b[0] + Sg * C0;
    __syncthreads();
    const int t = T0 + tid;
    float v = cst;
#pragma unroll 1
    for (int c = 0; c < NBANDS; ++c) {
        float a = 0.f;
#pragma unroll
        for (int m = 0; m < 25; ++m) a = fmaf(H[c][m], sh[c][tid + 4 + m], a);
        v += a;
    }
    if (t < 7 || (t >= T_LEN - 7 && t < T_LEN)) {
        v = g_b[0];
        for (int jj = 0; jj < 15; ++jj) {
            int tp = t + jj - 7;
            if (tp < 0 || tp >= T_LEN) continue;
            float xm = C0;
            for (int c = 0; c < NBANDS; ++c) {
                float mw = mix_w[c];
                for (int k = 0; k < 11; ++k) {
                    int i = tp + k + 11 - T0;
                    xm = fmaf(mw * ((k == 5 ? 1.f : 0.f) - la_w[c * 11 + k]),
                              sh[c][i], xm);
                }
            }
            v = fmaf(g_w[jj], xm, v);
        }
    }
    float vmax = 0.f;
    if (t < T_LEN) {
        v = fmaxf(v, 0.f);
        xg[(size_t)b * T_LEN + t] = v;
        vmax = v;
    }
#pragma unroll
    for (int off = 32; off > 0; off >>= 1) vmax = fmaxf(vmax, __shfl_down(vmax, off));
    if ((tid & 63) == 0) red[tid >> 6] = vmax;
    __syncthreads();
    if (tid == 0) {
        float m = fmaxf(fmaxf(red[0], red[1]), fmaxf(red[2], red[3]));
        atomicMax(&m1_bits[b], __float_as_int(m));
    }
}

// ---------------- K3a: xg -> spectral_flux out + fa (sigmoid) + max(fa)
__global__ __launch_bounds__(256) void k3a(
        const float* __restrict__ xg, const int* __restrict__ m1_bits,
        const float* __restrict__ fc_w, const float* __restrict__ fc_b,
        const float* __restrict__ fg_w, const float* __restrict__ fg_b,
        float* __restrict__ sf_out, float* __restrict__ fa_out,
        int* __restrict__ m2_bits) {
    __shared__ float shfm[272];
    __shared__ float red[4];
    const int tid = threadIdx.x;
    const int t0 = blockIdx.x * 256;
    const int b = blockIdx.y;
    const float inv = 1.f / (__int_as_float(m1_bits[b]) + EPS);
    const float sfc = fc_w[0] + fc_w[1] + fc_w[2] + fc_w[3];
    const float fcb = fc_b[0];
    for (int i = tid; i < 270; i += 256) {
        int tt = t0 + i - 7;
        float v = 0.f;
        if (tt >= 0 && tt < T_LEN)
            v = fmaf(sfc, xg[(size_t)b * T_LEN + tt] * inv, fcb);
        shfm[i] = v;
    }
    __syncthreads();
    const int t = t0 + tid;
    float fs = fg_b[0];
#pragma unroll
    for (int k = 0; k < 15; ++k) fs = fmaf(fg_w[k], shfm[tid + k], fs);
    float sig = 1.f / (1.f + __expf(-fs));
    float v;
    if (t < T_LEN) {
        sf_out[(size_t)b * T_LEN + t] = xg[(size_t)b * T_LEN + t] * inv;
        fa_out[(size_t)b * T_LEN + t] = sig;
        v = sig;
    } else {
        v = 0.f;
    }
#pragma unroll
    for (int off = 32; off > 0; off >>= 1) v = fmaxf(v, __shfl_down(v, off));
    if ((tid & 63) == 0) red[tid >> 6] = v;
    __syncthreads();
    if (tid == 0) {
        float m = fmaxf(fmaxf(red[0], red[1]), fmaxf(red[2], red[3]));
        atomicMax(&m2_bits[b], __float_as_int(m));
    }
}

// ---------------- K3b: fused_nov = fa / (m2 + eps), in-place
__global__ void k3b(float* __restrict__ fa, const int* __restrict__ m2_bits) {
    int idx = blockIdx.x * 256 + threadIdx.x;
    if (idx >= BATCH * T_LEN) return;
    int b = idx / T_LEN;
    float inv = 1.f / (__int_as_float(m2_bits[b]) + EPS);
    fa[idx] = fa[idx] * inv;
}

extern "C" void kernel_launch(void* const* d_in, const int* in_sizes, int n_in,
                              void* d_out, int out_size, void* d_ws, size_t ws_size,
                              hipStream_t stream) {
    const float* x    = (const float*)d_in[0];
    const float* lg   = (const float*)d_in[1];
    const float* dw   = (const float*)d_in[2];
    const float* db   = (const float*)d_in[3];
    const float* law  = (const float*)d_in[4];
    const float* lab  = (const float*)d_in[5];
    const float* mixw = (const float*)d_in[6];
    const float* gw   = (const float*)d_in[7];
    const float* gb   = (const float*)d_in[8];
    const float* fcw  = (const float*)d_in[9];
    const float* fcb  = (const float*)d_in[10];
    const float* fgw  = (const float*)d_in[11];
    const float* fgb  = (const float*)d_in[12];

    float* ws = (float*)d_ws;
    float* xp = ws;                                   // 4*8*60000 floats
    float* xg = ws + (size_t)BATCH * NBANDS * T_LEN;  // 240,000 floats
    int*   m1 = (int*)(xg + (size_t)BATCH * T_LEN);   // m1[4] then m2[4]

    float* sf_out = (float*)d_out;
    float* fn_out = sf_out + (size_t)BATCH * T_LEN;

    const int tb256 = (T_LEN + 255) / 256;

    k1_xp<<<dim3(K1_NBX, NBANDS, BATCH), dim3(256),
            FB * K1_ROWLEN * sizeof(float), stream>>>(
        x, lg, dw, db, xp, m1);
    k2_xg<<<dim3(tb256, BATCH), dim3(256), 0, stream>>>(
        xp, law, lab, mixw, gw, gb, xg, m1);
    k3a<<<dim3(tb256, BATCH), dim3(256), 0, stream>>>(
        xg, m1, fcw, fcb, fgw, fgb, sf_out, fn_out, m1 + 4);
    k3b<<<dim3((BATCH * T_LEN + 255) / 256), dim3(256), 0, stream>>>(fn_out, m1 + 4);
}